// Round 1
// baseline (204.283 us; speedup 1.0000x reference)
//
#include <hip/hip_runtime.h>

// Problem: S=8192, K=1024, O=4096
// out_q[s,o] = clip(round(int8dot(x[s,:], w[o,:]) * sx*sw/sy[s]), -128, 127)
// d_out = [ out_q as float (S*O) | scale_y (S) ]

#define S_DIM 8192
#define K_DIM 1024
#define O_DIM 4096
#define BM 128
#define BN 128
#define BK 64

using i32x4 = __attribute__((ext_vector_type(4))) int;

__device__ __forceinline__ void load_lds16(const void* g, void* l) {
  __builtin_amdgcn_global_load_lds(
      (const __attribute__((address_space(1))) void*)g,
      (__attribute__((address_space(3))) void*)l, 16, 0, 0);
}

// ---------------- pack: int32 -> int8 for x and w, plus scale_y passthrough ----
__global__ void pack_kernel(const int* __restrict__ xi, const int* __restrict__ wi,
                            const float* __restrict__ sy,
                            unsigned int* __restrict__ xq, unsigned int* __restrict__ wq,
                            float* __restrict__ out_sy) {
  const int idx = blockIdx.x * blockDim.x + threadIdx.x;
  const int nx = S_DIM * K_DIM / 4;  // 2M packed words
  const int nw = O_DIM * K_DIM / 4;  // 1M packed words
  if (idx < nx) {
    int4 v = ((const int4*)xi)[idx];
    unsigned int p = (v.x & 0xff) | ((v.y & 0xff) << 8) |
                     ((v.z & 0xff) << 16) | ((unsigned)(v.w & 0xff) << 24);
    xq[idx] = p;
  } else if (idx < nx + nw) {
    const int j = idx - nx;
    int4 v = ((const int4*)wi)[j];
    unsigned int p = (v.x & 0xff) | ((v.y & 0xff) << 8) |
                     ((v.z & 0xff) << 16) | ((unsigned)(v.w & 0xff) << 24);
    wq[j] = p;
  }
  if (idx < S_DIM) out_sy[idx] = sy[idx];
}

// ---------------- int8 MFMA GEMM, m97-style structure -------------------------
// Block: 256 threads = 4 waves in 2x2; each wave owns a 64x64 sub-tile as a
// 4x4 grid of 16x16 MFMA tiles. BK=64 -> one mfma_i32_16x16x64_i8 per tile
// per K-step. LDS tiles row-major [128][64] int8 (8 KB each), staged with
// global_load_lds width=16 (LDS dest = wave-uniform base + lane*16).
__global__ __launch_bounds__(256) void gemm_i8_kernel(
    const signed char* __restrict__ A,   // packed x [S,K] int8
    const signed char* __restrict__ B,   // packed w [O,K] int8
    const float* __restrict__ sx, const float* __restrict__ sw,
    const float* __restrict__ sy, float* __restrict__ out) {
  __shared__ __align__(16) signed char As[BM * BK];
  __shared__ __align__(16) signed char Bs[BN * BK];

  const int tid = threadIdx.x;
  const int wave = tid >> 6;
  const int lane = tid & 63;
  const int wm = wave >> 1;  // 0..1: wave row in block
  const int wn = wave & 1;   // 0..1: wave col in block
  const int rowBase = blockIdx.y * BM;
  const int colBase = blockIdx.x * BN;

  // Staging: each wave fills 1 KB chunks. Round r (r=0,1) covers block rows
  // [r*64, r*64+64): lane -> row = r*64 + wave*16 + lane/4, col = (lane%4)*16.
  // LDS byte for that element = r*4096 + wave*1024 + lane*16 (wave-uniform base).
  const int sRow = wave * 16 + (lane >> 2);
  const int sCol = (lane & 3) * 16;
  const signed char* gA = A + (size_t)(rowBase + sRow) * K_DIM + sCol;
  const signed char* gB = B + (size_t)(colBase + sRow) * K_DIM + sCol;
  signed char* lA = As + wave * 1024;
  signed char* lB = Bs + wave * 1024;

  i32x4 acc[4][4] = {};

  const int fr = lane & 15;          // row within 16x16 fragment (A/B operand m/n)
  const int fq = (lane >> 4) * 16;   // K-chunk byte offset for this quad

  for (int k0 = 0; k0 < K_DIM; k0 += BK) {
    load_lds16(gA + k0, lA);
    load_lds16(gA + (size_t)64 * K_DIM + k0, lA + 4096);
    load_lds16(gB + k0, lB);
    load_lds16(gB + (size_t)64 * K_DIM + k0, lB + 4096);
    __syncthreads();

    i32x4 af[4], bf[4];
#pragma unroll
    for (int mi = 0; mi < 4; ++mi)
      af[mi] = *(const i32x4*)(As + (wm * 64 + mi * 16 + fr) * BK + fq);
#pragma unroll
    for (int ni = 0; ni < 4; ++ni)
      bf[ni] = *(const i32x4*)(Bs + (wn * 64 + ni * 16 + fr) * BK + fq);

#pragma unroll
    for (int mi = 0; mi < 4; ++mi)
#pragma unroll
      for (int ni = 0; ni < 4; ++ni)
        acc[mi][ni] =
            __builtin_amdgcn_mfma_i32_16x16x64_i8(af[mi], bf[ni], acc[mi][ni], 0, 0, 0);
    __syncthreads();
  }

  // Epilogue. C/D layout: col = lane&15, row = (lane>>4)*4 + reg.
  const float sxw = sx[0] * sw[0];
  const int quad = lane >> 4;
#pragma unroll
  for (int mi = 0; mi < 4; ++mi) {
#pragma unroll
    for (int r = 0; r < 4; ++r) {
      const int s = rowBase + wm * 64 + mi * 16 + quad * 4 + r;
      const float rs = sxw / sy[s];
      float* orow = out + (size_t)s * O_DIM + colBase + wn * 64 + fr;
#pragma unroll
      for (int ni = 0; ni < 4; ++ni) {
        float f = rintf((float)acc[mi][ni][r] * rs);
        f = fminf(127.0f, fmaxf(-128.0f, f));
        orow[ni * 16] = f;
      }
    }
  }
}

extern "C" void kernel_launch(void* const* d_in, const int* in_sizes, int n_in,
                              void* d_out, int out_size, void* d_ws, size_t ws_size,
                              hipStream_t stream) {
  const int* x = (const int*)d_in[0];        // [S,K] int8 values as int32
  const int* w = (const int*)d_in[1];        // [O,K] int8 values as int32
  const float* sx = (const float*)d_in[2];
  const float* sw = (const float*)d_in[3];
  const float* sy = (const float*)d_in[4];   // [S]
  float* out = (float*)d_out;

  unsigned int* xq = (unsigned int*)d_ws;                         // 8 MB
  unsigned int* wq = xq + (size_t)S_DIM * K_DIM / 4;              // 4 MB

  const int total = S_DIM * K_DIM / 4 + O_DIM * K_DIM / 4;  // 3M threads
  pack_kernel<<<(total + 255) / 256, 256, 0, stream>>>(
      x, w, sy, xq, wq, out + (size_t)S_DIM * O_DIM);

  dim3 grid(O_DIM / BN, S_DIM / BM);  // (32, 64)
  gemm_i8_kernel<<<grid, 256, 0, stream>>>(
      (const signed char*)xq, (const signed char*)wq, sx, sw, sy, out);
}